// Round 1
// 596.610 us; speedup vs baseline: 1.1295x; 1.1295x over previous
//
#include <hip/hip_runtime.h>
#include <math.h>

#define SEQ   2048
#define BATCH 2
#define NHEAD 8
#define HID   512
#define LG8   0.180336880f   /* log2(e)/8 : folded softmax scale */
#define MASKV -3.0e8f

typedef unsigned char  u8;
typedef unsigned short u16;
typedef short short8 __attribute__((ext_vector_type(8)));
typedef float f32x4  __attribute__((ext_vector_type(4)));

__device__ __forceinline__ u16 f2bf(float f) {
    unsigned u = __float_as_uint(f);
    u = (u + 0x7FFF + ((u >> 16) & 1)) >> 16;   // RNE
    return (u16)u;
}
__device__ __forceinline__ float bf2f(u16 h) {
    return __uint_as_float(((unsigned)h) << 16);
}

// ---------------- prep weights: Wt[n][k] (transposed) split to bf16 hi/lo ----------------
__global__ __launch_bounds__(256) void prep_w_kernel(
    const float* __restrict__ W, u16* __restrict__ Wth, u16* __restrict__ Wtl)
{
    __shared__ float Ws[64][68];
    const int tid = threadIdx.x;
    const int k0 = blockIdx.x << 6;
    const int n0 = blockIdx.y << 6;
    const int rr = tid >> 2, c4 = (tid & 3) << 4;
    #pragma unroll
    for (int e = 0; e < 4; ++e) {
        float4 v = *(const float4*)&W[(size_t)(k0 + rr) * HID + n0 + c4 + (e << 2)];
        *(float4*)&Ws[rr][c4 + (e << 2)] = v;
    }
    __syncthreads();
    const int nn = tid >> 2, kk = (tid & 3) << 4;
    u16 hb[16], lb[16];
    #pragma unroll
    for (int e = 0; e < 16; ++e) {
        float x = Ws[kk + e][nn];
        u16 hi = f2bf(x);
        hb[e] = hi;
        lb[e] = f2bf(x - bf2f(hi));
    }
    const size_t o = (size_t)(n0 + nn) * HID + k0 + kk;
    *(short8*)&Wth[o]     = *(short8*)&hb[0];
    *(short8*)&Wth[o + 8] = *(short8*)&hb[8];
    *(short8*)&Wtl[o]     = *(short8*)&lb[0];
    *(short8*)&Wtl[o + 8] = *(short8*)&lb[8];
}

// ---------------- split fp32 activations -> bf16 hi/lo ----------------
__global__ __launch_bounds__(256) void convert_split_kernel(
    const float* __restrict__ src, u16* __restrict__ h, u16* __restrict__ l)
{
    const size_t i = ((size_t)blockIdx.x * 256 + threadIdx.x) * 4;
    float4 v = *(const float4*)&src[i];
    ushort4 oh, ol; u16 hh;
    hh = f2bf(v.x); oh.x = hh; ol.x = f2bf(v.x - bf2f(hh));
    hh = f2bf(v.y); oh.y = hh; ol.y = f2bf(v.y - bf2f(hh));
    hh = f2bf(v.z); oh.z = hh; ol.z = f2bf(v.z - bf2f(hh));
    hh = f2bf(v.w); oh.w = hh; ol.w = f2bf(v.w - bf2f(hh));
    *(ushort4*)&h[i] = oh; *(ushort4*)&l[i] = ol;
}

// ---------------- MFMA GEMM: C[M,512] = A @ W + bias, bf16 hi/lo 3-product ----------------
// MODE 0: fp32 out (Wo). MODE 1: q -> qh/ql prescaled by LG8. MODE 2: k -> kh/kl. MODE 3: v -> vb.
template<int MODE>
__global__ __launch_bounds__(256) void gemm_mfma_kernel(
    const u16* __restrict__ Ah, const u16* __restrict__ Al,
    const u16* __restrict__ Wth, const u16* __restrict__ Wtl,
    const float* __restrict__ bias,
    float* __restrict__ Cf, u16* __restrict__ Oh, u16* __restrict__ Ol)
{
    __shared__ __align__(16) u16 Sa_h[64 * 72];
    __shared__ __align__(16) u16 Sa_l[64 * 72];
    __shared__ __align__(16) u16 Sw_h[64 * 72];
    __shared__ __align__(16) u16 Sw_l[64 * 72];
    const int tid = threadIdx.x;
    const int wave = tid >> 6, lane = tid & 63;
    const int quad = lane >> 4, l15 = lane & 15;
    const int row0 = blockIdx.x << 6, col0 = blockIdx.y << 6;
    const int rr = tid >> 2, cc = (tid & 3) << 4;

    const size_t ga = (size_t)(row0 + rr) * HID + cc;
    const size_t gw = (size_t)(col0 + rr) * HID + cc;

    f32x4 acc[4] = {{0.f,0.f,0.f,0.f},{0.f,0.f,0.f,0.f},{0.f,0.f,0.f,0.f},{0.f,0.f,0.f,0.f}};

    for (int k0 = 0; k0 < HID; k0 += 64) {
        const short8 ah0 = *(const short8*)&Ah[ga + k0];
        const short8 ah1 = *(const short8*)&Ah[ga + k0 + 8];
        const short8 al0 = *(const short8*)&Al[ga + k0];
        const short8 al1 = *(const short8*)&Al[ga + k0 + 8];
        const short8 wh0 = *(const short8*)&Wth[gw + k0];
        const short8 wh1 = *(const short8*)&Wth[gw + k0 + 8];
        const short8 wl0 = *(const short8*)&Wtl[gw + k0];
        const short8 wl1 = *(const short8*)&Wtl[gw + k0 + 8];
        __syncthreads();
        *(short8*)&Sa_h[rr * 72 + cc]     = ah0;
        *(short8*)&Sa_h[rr * 72 + cc + 8] = ah1;
        *(short8*)&Sa_l[rr * 72 + cc]     = al0;
        *(short8*)&Sa_l[rr * 72 + cc + 8] = al1;
        *(short8*)&Sw_h[rr * 72 + cc]     = wh0;
        *(short8*)&Sw_h[rr * 72 + cc + 8] = wh1;
        *(short8*)&Sw_l[rr * 72 + cc]     = wl0;
        *(short8*)&Sw_l[rr * 72 + cc + 8] = wl1;
        __syncthreads();
        #pragma unroll
        for (int s = 0; s < 2; ++s) {
            const int ao = ((wave << 4) + l15) * 72 + (s << 5) + (quad << 3);
            const short8 fa_h = *(const short8*)&Sa_h[ao];
            const short8 fa_l = *(const short8*)&Sa_l[ao];
            #pragma unroll
            for (int nt = 0; nt < 4; ++nt) {
                const int bo = ((nt << 4) + l15) * 72 + (s << 5) + (quad << 3);
                const short8 fb_h = *(const short8*)&Sw_h[bo];
                const short8 fb_l = *(const short8*)&Sw_l[bo];
                acc[nt] = __builtin_amdgcn_mfma_f32_16x16x32_bf16(fa_h, fb_h, acc[nt], 0, 0, 0);
                acc[nt] = __builtin_amdgcn_mfma_f32_16x16x32_bf16(fa_l, fb_h, acc[nt], 0, 0, 0);
                acc[nt] = __builtin_amdgcn_mfma_f32_16x16x32_bf16(fa_h, fb_l, acc[nt], 0, 0, 0);
            }
        }
    }
    #pragma unroll
    for (int nt = 0; nt < 4; ++nt) {
        const int col = col0 + (nt << 4) + l15;
        const float bv = bias[col];
        #pragma unroll
        for (int r = 0; r < 4; ++r) {
            const size_t row = (size_t)(row0 + (wave << 4) + (quad << 2) + r);
            const float v = acc[nt][r] + bv;
            if constexpr (MODE == 0) {
                Cf[row * HID + col] = v;
            } else if constexpr (MODE == 1) {
                const float sv = v * LG8;
                const u16 hi = f2bf(sv);
                Oh[row * HID + col] = hi;
                Ol[row * HID + col] = f2bf(sv - bf2f(hi));
            } else if constexpr (MODE == 2) {
                const u16 hi = f2bf(v);
                Oh[row * HID + col] = hi;
                Ol[row * HID + col] = f2bf(v - bf2f(hi));
            } else {
                Oh[row * HID + col] = f2bf(v);
            }
        }
    }
}

// ---------------- fused pos/mask byte table: pm = mask ? 3 : pos ----------------
__global__ __launch_bounds__(256) void convert_pm_kernel(
    const int* __restrict__ pos, const u8* __restrict__ mask, u8* __restrict__ pm)
{
    const size_t s = ((size_t)blockIdx.x * 256 + threadIdx.x) * 4;
    int4  p = *(const int4*)&pos[s & (size_t)(SEQ * SEQ - 1)];
    uchar4 m = *(const uchar4*)&mask[s];
    uchar4 o;
    o.x = m.x ? (u8)3 : (u8)p.x;
    o.y = m.y ? (u8)3 : (u8)p.y;
    o.z = m.z ? (u8)3 : (u8)p.z;
    o.w = m.w ? (u8)3 : (u8)p.w;
    *(uchar4*)&pm[s] = o;
}

// ---------------- rel dots from bf16 hi/lo (q prescaled by LG8) ----------------
// dqk[bh,i,r] = LG8 * sum_d (q+k)[b,i,h,d] * rel_table[r,d]
__global__ __launch_bounds__(256) void rel_dots_kernel(
    const u16* __restrict__ qh, const u16* __restrict__ ql,
    const u16* __restrict__ kh, const u16* __restrict__ kl,
    const float* __restrict__ rel_table, float* __restrict__ dqk)
{
    const int w = blockIdx.x * 4 + (threadIdx.x >> 6);
    const int lane = threadIdx.x & 63;
    const int h = w % NHEAD;
    const int is = w / NHEAD;            // b*SEQ + i
    const int b = is / SEQ;
    const int i = is % SEQ;
    const size_t base = (size_t)is * HID + h * 64 + lane;
    const float qs = bf2f(qh[base]) + bf2f(ql[base]);   // = q * LG8
    const float kv = bf2f(kh[base]) + bf2f(kl[base]);   // = k
    const float s = qs + LG8 * kv;
    float p0 = s * rel_table[lane];
    float p1 = s * rel_table[64 + lane];
    float p2 = s * rel_table[128 + lane];
    #pragma unroll
    for (int off = 32; off; off >>= 1) {
        p0 += __shfl_xor(p0, off);
        p1 += __shfl_xor(p1, off);
        p2 += __shfl_xor(p2, off);
    }
    if (lane == 0) {
        size_t o = (((size_t)b * NHEAD + h) * SEQ + i) << 2;
        dqk[o + 0] = p0; dqk[o + 1] = p1; dqk[o + 2] = p2;
    }
}

// ---------------- pass 1: per-row denominator (no logits write) ----------------
// block = (i-tile 64, h, b), 4 waves; wave w owns rows w*16..w*16+15 (MFMA M).
__global__ __launch_bounds__(256) void attn_stats_kernel(
    const u16* __restrict__ qh, const u16* __restrict__ ql,
    const u16* __restrict__ kh, const u16* __restrict__ kl,
    const float* __restrict__ dqk, const u8* __restrict__ pm,
    float* __restrict__ invl)
{
    __shared__ __align__(16) u16 Kh[64 * 72];
    __shared__ __align__(16) u16 Kl[64 * 72];
    __shared__ __align__(16) u8  PM[64 * 64];
    __shared__ float Ds[64][4];
    const int tid = threadIdx.x;
    const int wave = tid >> 6, lane = tid & 63;
    const int quad = lane >> 4, l15 = lane & 15;
    const int b = blockIdx.z, h = blockIdx.y, i0 = blockIdx.x << 6;
    const size_t bh = (size_t)(b * NHEAD + h);

    {
        const int i = tid >> 2, r = tid & 3;
        Ds[i][r] = (r == 3) ? MASKV : dqk[((bh * SEQ + i0 + i) << 2) + r];
    }
    const int irow = (wave << 4) + l15;
    const size_t qbase = ((size_t)(b * SEQ + i0 + irow)) * HID + h * 64 + (quad << 3);
    const short8 aqh0 = *(const short8*)&qh[qbase];
    const short8 aqh1 = *(const short8*)&qh[qbase + 32];
    const short8 aql0 = *(const short8*)&ql[qbase];
    const short8 aql1 = *(const short8*)&ql[qbase + 32];

    float srow[4] = {0.f, 0.f, 0.f, 0.f};

    for (int jt = 0; jt < SEQ / 64; ++jt) {
        const int j0 = jt << 6;
        __syncthreads();
        {
            const int rr = tid >> 3, cc = (tid & 7) << 3;
            const size_t g = ((size_t)(b * SEQ + j0 + rr)) * HID + h * 64 + cc;
            *(short8*)&Kh[rr * 72 + cc] = *(const short8*)&kh[g];
            *(short8*)&Kl[rr * 72 + cc] = *(const short8*)&kl[g];
            const size_t g2 = g + (size_t)32 * HID;
            *(short8*)&Kh[(rr + 32) * 72 + cc] = *(const short8*)&kh[g2];
            *(short8*)&Kl[(rr + 32) * 72 + cc] = *(const short8*)&kl[g2];
        }
        {
            const int r = tid >> 2, c = (tid & 3) << 4;
            *(uint4*)&PM[r * 64 + c] =
                *(const uint4*)&pm[((size_t)b * SEQ + i0 + r) * SEQ + j0 + c];
        }
        __syncthreads();

        #pragma unroll
        for (int sub = 0; sub < 4; ++sub) {
            const int n = (sub << 4) + l15;
            const short8 bh0 = *(const short8*)&Kh[n * 72 + (quad << 3)];
            const short8 bh1 = *(const short8*)&Kh[n * 72 + 32 + (quad << 3)];
            const short8 bl0 = *(const short8*)&Kl[n * 72 + (quad << 3)];
            const short8 bl1 = *(const short8*)&Kl[n * 72 + 32 + (quad << 3)];
            f32x4 acc = {0.f, 0.f, 0.f, 0.f};
            acc = __builtin_amdgcn_mfma_f32_16x16x32_bf16(aqh0, bh0, acc, 0, 0, 0);
            acc = __builtin_amdgcn_mfma_f32_16x16x32_bf16(aqh1, bh1, acc, 0, 0, 0);
            acc = __builtin_amdgcn_mfma_f32_16x16x32_bf16(aql0, bh0, acc, 0, 0, 0);
            acc = __builtin_amdgcn_mfma_f32_16x16x32_bf16(aql1, bh1, acc, 0, 0, 0);
            acc = __builtin_amdgcn_mfma_f32_16x16x32_bf16(aqh0, bl0, acc, 0, 0, 0);
            acc = __builtin_amdgcn_mfma_f32_16x16x32_bf16(aqh1, bl1, acc, 0, 0, 0);
            #pragma unroll
            for (int r = 0; r < 4; ++r) {
                const int il = (wave << 4) + (quad << 2) + r;
                const u8 p = PM[il * 64 + (sub << 4) + l15];
                srow[r] += exp2f(acc[r] + Ds[il][p]);
            }
        }
    }
    #pragma unroll
    for (int r = 0; r < 4; ++r) {
        float s = srow[r];
        s += __shfl_xor(s, 1); s += __shfl_xor(s, 2);
        s += __shfl_xor(s, 4); s += __shfl_xor(s, 8);
        if (l15 == 0)
            invl[bh * SEQ + i0 + (wave << 4) + (quad << 2) + r] = 1.0f / s;
    }
}

// ---------------- pass 2: recompute logits, write attn once, fused PV ----------------
__global__ __launch_bounds__(256) void attn_fused_kernel(
    const u16* __restrict__ qh, const u16* __restrict__ ql,
    const u16* __restrict__ kh, const u16* __restrict__ kl,
    const u16* __restrict__ vb, const float* __restrict__ dqk,
    const u8* __restrict__ pm, const float* __restrict__ invl,
    float* __restrict__ attn, float* __restrict__ x)
{
    __shared__ __align__(16) u16 Kh[64 * 72];
    __shared__ __align__(16) u16 Kl[64 * 72];
    __shared__ __align__(16) u16 VtT[64 * 72];
    __shared__ __align__(16) u16 Pst[4][16 * 72];
    __shared__ __align__(16) u8  PM[64 * 64];
    __shared__ float Ds[64][4];
    const int tid = threadIdx.x;
    const int wave = tid >> 6, lane = tid & 63;
    const int quad = lane >> 4, l15 = lane & 15;
    const int b = blockIdx.z, h = blockIdx.y, i0 = blockIdx.x << 6;
    const size_t bh = (size_t)(b * NHEAD + h);

    {
        const int i = tid >> 2, r = tid & 3;
        Ds[i][r] = (r == 3) ? MASKV : dqk[((bh * SEQ + i0 + i) << 2) + r];
    }
    float inv_r[4];
    #pragma unroll
    for (int r = 0; r < 4; ++r)
        inv_r[r] = invl[bh * SEQ + i0 + (wave << 4) + (quad << 2) + r];

    const int irow = (wave << 4) + l15;
    const size_t qbase = ((size_t)(b * SEQ + i0 + irow)) * HID + h * 64 + (quad << 3);
    const short8 aqh0 = *(const short8*)&qh[qbase];
    const short8 aqh1 = *(const short8*)&qh[qbase + 32];
    const short8 aql0 = *(const short8*)&ql[qbase];
    const short8 aql1 = *(const short8*)&ql[qbase + 32];

    f32x4 accX[4] = {{0.f,0.f,0.f,0.f},{0.f,0.f,0.f,0.f},{0.f,0.f,0.f,0.f},{0.f,0.f,0.f,0.f}};

    for (int jt = 0; jt < SEQ / 64; ++jt) {
        const int j0 = jt << 6;
        __syncthreads();
        {
            const int rr = tid >> 3, cc = (tid & 7) << 3;
            const size_t g = ((size_t)(b * SEQ + j0 + rr)) * HID + h * 64 + cc;
            *(short8*)&Kh[rr * 72 + cc] = *(const short8*)&kh[g];
            *(short8*)&Kl[rr * 72 + cc] = *(const short8*)&kl[g];
            const size_t g2 = g + (size_t)32 * HID;
            *(short8*)&Kh[(rr + 32) * 72 + cc] = *(const short8*)&kh[g2];
            *(short8*)&Kl[(rr + 32) * 72 + cc] = *(const short8*)&kl[g2];
        }
        {
            const int r = tid >> 2, c = (tid & 3) << 4;
            *(uint4*)&PM[r * 64 + c] =
                *(const uint4*)&pm[((size_t)b * SEQ + i0 + r) * SEQ + j0 + c];
        }
        {   // stage V^T tile (d-major) for PV A-operand
            const int jr = tid & 63, d0 = (tid >> 6) << 4;
            const size_t g = ((size_t)(b * SEQ + j0 + jr)) * HID + h * 64 + d0;
            const short8 v0 = *(const short8*)&vb[g];
            const short8 v1 = *(const short8*)&vb[g + 8];
            #pragma unroll
            for (int e = 0; e < 8; ++e) {
                VtT[(d0 + e) * 72 + jr]     = (u16)v0[e];
                VtT[(d0 + 8 + e) * 72 + jr] = (u16)v1[e];
            }
        }
        __syncthreads();

        #pragma unroll
        for (int sub = 0; sub < 4; ++sub) {
            const int n = (sub << 4) + l15;
            const short8 bh0 = *(const short8*)&Kh[n * 72 + (quad << 3)];
            const short8 bh1 = *(const short8*)&Kh[n * 72 + 32 + (quad << 3)];
            const short8 bl0 = *(const short8*)&Kl[n * 72 + (quad << 3)];
            const short8 bl1 = *(const short8*)&Kl[n * 72 + 32 + (quad << 3)];
            f32x4 acc = {0.f, 0.f, 0.f, 0.f};
            acc = __builtin_amdgcn_mfma_f32_16x16x32_bf16(aqh0, bh0, acc, 0, 0, 0);
            acc = __builtin_amdgcn_mfma_f32_16x16x32_bf16(aqh1, bh1, acc, 0, 0, 0);
            acc = __builtin_amdgcn_mfma_f32_16x16x32_bf16(aql0, bh0, acc, 0, 0, 0);
            acc = __builtin_amdgcn_mfma_f32_16x16x32_bf16(aql1, bh1, acc, 0, 0, 0);
            acc = __builtin_amdgcn_mfma_f32_16x16x32_bf16(aqh0, bl0, acc, 0, 0, 0);
            acc = __builtin_amdgcn_mfma_f32_16x16x32_bf16(aqh1, bl1, acc, 0, 0, 0);
            #pragma unroll
            for (int r = 0; r < 4; ++r) {
                const int il = (wave << 4) + (quad << 2) + r;
                const u8 p = PM[il * 64 + (sub << 4) + l15];
                const float pr = exp2f(acc[r] + Ds[il][p]) * inv_r[r];
                attn[(bh * SEQ + i0 + il) * SEQ + j0 + (sub << 4) + l15] = pr;
                Pst[wave][((quad << 2) + r) * 72 + (sub << 4) + l15] = f2bf(pr);
            }
        }
        // PV: X^T = V^T @ P^T  (wave-private P strip; same-wave LDS ordering)
        const short8 bp0 = *(const short8*)&Pst[wave][l15 * 72 + (quad << 3)];
        const short8 bp1 = *(const short8*)&Pst[wave][l15 * 72 + 32 + (quad << 3)];
        #pragma unroll
        for (int m = 0; m < 4; ++m) {
            const short8 av0 = *(const short8*)&VtT[((m << 4) + l15) * 72 + (quad << 3)];
            const short8 av1 = *(const short8*)&VtT[((m << 4) + l15) * 72 + 32 + (quad << 3)];
            accX[m] = __builtin_amdgcn_mfma_f32_16x16x32_bf16(av0, bp0, accX[m], 0, 0, 0);
            accX[m] = __builtin_amdgcn_mfma_f32_16x16x32_bf16(av1, bp1, accX[m], 0, 0, 0);
        }
    }
    const size_t xrow = ((size_t)(b * SEQ + i0 + (wave << 4) + l15)) * HID + h * 64;
    #pragma unroll
    for (int m = 0; m < 4; ++m) {
        *(f32x4*)&x[xrow + (m << 4) + (quad << 2)] = accX[m];
    }
}

extern "C" void kernel_launch(void* const* d_in, const int* in_sizes, int n_in,
                              void* d_out, int out_size, void* d_ws, size_t ws_size,
                              hipStream_t stream) {
    (void)in_sizes; (void)n_in; (void)out_size; (void)ws_size;
    const float* query = (const float*)d_in[0];
    const float* key_  = (const float*)d_in[1];
    const float* value = (const float*)d_in[2];
    const u8*    mask  = (const u8*)d_in[3];
    const int*   pos   = (const int*)d_in[4];
    const float* Wq = (const float*)d_in[5];
    const float* bq = (const float*)d_in[6];
    const float* Wk = (const float*)d_in[7];
    const float* bk = (const float*)d_in[8];
    const float* Wv = (const float*)d_in[9];
    const float* bv = (const float*)d_in[10];
    const float* Wo = (const float*)d_in[11];
    const float* bo = (const float*)d_in[12];
    const float* rel_table = (const float*)d_in[13];

    float* out  = (float*)d_out;
    float* attn = out + (size_t)BATCH * SEQ * HID;

    // ws layout: qh|ql|kh|kl|vb bf16 (4MB ea) | dqk 512KB | invl 128KB | pm 8MB |
    //            x_ws 8MB | bufAh|bufAl bf16 (4MB ea) | Wth|Wtl (512KB ea)  ~45.6MB
    u16* qh = (u16*)d_ws;
    u16* ql = qh + (size_t)2097152;
    u16* kh = ql + (size_t)2097152;
    u16* kl = kh + (size_t)2097152;
    u16* vb = kl + (size_t)2097152;
    float* dqk  = (float*)(vb + (size_t)2097152);
    float* invl = dqk + (size_t)131072;
    u8*  pm  = (u8*)(invl + (size_t)32768);
    float* x_ws = (float*)(pm + (size_t)8388608);
    u16* bufAh = (u16*)(x_ws + (size_t)2097152);
    u16* bufAl = bufAh + (size_t)2097152;
    u16* Wth = bufAl + (size_t)2097152;
    u16* Wtl = Wth + (size_t)262144;

    const dim3 blk(256);
    const dim3 gemm_grid(64, 8);   // (M/64, HID/64)
    const dim3 prep_grid(8, 8);

    // Q projection -> qh/ql (prescaled LG8)
    prep_w_kernel<<<prep_grid, blk, 0, stream>>>(Wq, Wth, Wtl);
    convert_split_kernel<<<dim3(2048), blk, 0, stream>>>(query, bufAh, bufAl);
    gemm_mfma_kernel<1><<<gemm_grid, blk, 0, stream>>>(bufAh, bufAl, Wth, Wtl, bq,
                                                       nullptr, qh, ql);
    // K projection -> kh/kl
    prep_w_kernel<<<prep_grid, blk, 0, stream>>>(Wk, Wth, Wtl);
    convert_split_kernel<<<dim3(2048), blk, 0, stream>>>(key_, bufAh, bufAl);
    gemm_mfma_kernel<2><<<gemm_grid, blk, 0, stream>>>(bufAh, bufAl, Wth, Wtl, bk,
                                                       nullptr, kh, kl);
    // V projection -> vb
    prep_w_kernel<<<prep_grid, blk, 0, stream>>>(Wv, Wth, Wtl);
    convert_split_kernel<<<dim3(2048), blk, 0, stream>>>(value, bufAh, bufAl);
    gemm_mfma_kernel<3><<<gemm_grid, blk, 0, stream>>>(bufAh, bufAl, Wth, Wtl, bv,
                                                       nullptr, vb, nullptr);

    rel_dots_kernel<<<dim3(BATCH * SEQ * NHEAD / 4), blk, 0, stream>>>(
        qh, ql, kh, kl, rel_table, dqk);
    convert_pm_kernel<<<dim3(8192), blk, 0, stream>>>(pos, mask, pm);
    attn_stats_kernel<<<dim3(SEQ / 64, NHEAD, BATCH), blk, 0, stream>>>(
        qh, ql, kh, kl, dqk, pm, invl);
    attn_fused_kernel<<<dim3(SEQ / 64, NHEAD, BATCH), blk, 0, stream>>>(
        qh, ql, kh, kl, vb, dqk, pm, invl, attn, x_ws);

    // out = x @ Wo + bo
    prep_w_kernel<<<prep_grid, blk, 0, stream>>>(Wo, Wth, Wtl);
    convert_split_kernel<<<dim3(2048), blk, 0, stream>>>(x_ws, bufAh, bufAl);
    gemm_mfma_kernel<0><<<gemm_grid, blk, 0, stream>>>(bufAh, bufAl, Wth, Wtl, bo,
                                                       out, nullptr, nullptr);
}

// Round 2
// 566.145 us; speedup vs baseline: 1.1902x; 1.0538x over previous
//
#include <hip/hip_runtime.h>
#include <math.h>

#define SEQ   2048
#define BATCH 2
#define NHEAD 8
#define HID   512
#define LG8   0.180336880f   /* log2(e)/8 : folded softmax scale */
#define MASKV -3.0e8f

typedef unsigned char  u8;
typedef unsigned short u16;
typedef short short8 __attribute__((ext_vector_type(8)));
typedef float f32x4  __attribute__((ext_vector_type(4)));

__device__ __forceinline__ u16 f2bf(float f) {
    unsigned u = __float_as_uint(f);
    u = (u + 0x7FFF + ((u >> 16) & 1)) >> 16;   // RNE
    return (u16)u;
}
__device__ __forceinline__ float bf2f(u16 h) {
    return __uint_as_float(((unsigned)h) << 16);
}

// ---------------- misc prep: 4x weight transpose/split (blocks 0..255) + pm table (blocks 256+) ----------------
__global__ __launch_bounds__(256) void misc_prep_kernel(
    const float* __restrict__ Wq, const float* __restrict__ Wk,
    const float* __restrict__ Wv, const float* __restrict__ Wo,
    u16* __restrict__ Wth, u16* __restrict__ Wtl,
    const int* __restrict__ pos, const u8* __restrict__ mask, u8* __restrict__ pm)
{
    __shared__ float Ws[64][68];
    const int tid = threadIdx.x;
    const int bid = blockIdx.x;
    if (bid < 256) {
        const int w = bid >> 6, sub = bid & 63;
        const float* W = (w == 0) ? Wq : (w == 1) ? Wk : (w == 2) ? Wv : Wo;
        u16* oth = Wth + (size_t)w * 262144;
        u16* otl = Wtl + (size_t)w * 262144;
        const int k0 = (sub & 7) << 6;
        const int n0 = (sub >> 3) << 6;
        const int rr = tid >> 2, c4 = (tid & 3) << 4;
        #pragma unroll
        for (int e = 0; e < 4; ++e) {
            float4 v = *(const float4*)&W[(size_t)(k0 + rr) * HID + n0 + c4 + (e << 2)];
            *(float4*)&Ws[rr][c4 + (e << 2)] = v;
        }
        __syncthreads();
        const int nn = tid >> 2, kk = (tid & 3) << 4;
        u16 hb[16], lb[16];
        #pragma unroll
        for (int e = 0; e < 16; ++e) {
            float x = Ws[kk + e][nn];
            u16 hi = f2bf(x);
            hb[e] = hi;
            lb[e] = f2bf(x - bf2f(hi));
        }
        const size_t o = (size_t)(n0 + nn) * HID + k0 + kk;
        *(short8*)&oth[o]     = *(short8*)&hb[0];
        *(short8*)&oth[o + 8] = *(short8*)&hb[8];
        *(short8*)&otl[o]     = *(short8*)&lb[0];
        *(short8*)&otl[o + 8] = *(short8*)&lb[8];
    } else {
        const size_t s = ((size_t)(bid - 256) * 256 + tid) * 4;
        int4  p = *(const int4*)&pos[s & (size_t)(SEQ * SEQ - 1)];
        uchar4 m = *(const uchar4*)&mask[s];
        uchar4 o;
        o.x = m.x ? (u8)3 : (u8)p.x;
        o.y = m.y ? (u8)3 : (u8)p.y;
        o.z = m.z ? (u8)3 : (u8)p.z;
        o.w = m.w ? (u8)3 : (u8)p.w;
        *(uchar4*)&pm[s] = o;
    }
}

// ---------------- fused QKV projection: z selects (A, W, bias, output mode) ----------------
// Reads fp32 activations, splits to bf16 hi/lo in-register during staging.
__global__ __launch_bounds__(256) void gemm_qkv_kernel(
    const float* __restrict__ query, const float* __restrict__ key_,
    const float* __restrict__ value,
    const u16* __restrict__ Wth_all, const u16* __restrict__ Wtl_all,
    const float* __restrict__ bq, const float* __restrict__ bk,
    const float* __restrict__ bv,
    u16* __restrict__ qh, u16* __restrict__ ql,
    u16* __restrict__ kh, u16* __restrict__ kl, u16* __restrict__ vb)
{
    __shared__ __align__(16) u16 Sa_h[64 * 72];
    __shared__ __align__(16) u16 Sa_l[64 * 72];
    __shared__ __align__(16) u16 Sw_h[64 * 72];
    __shared__ __align__(16) u16 Sw_l[64 * 72];
    const int z = blockIdx.z;
    const float* A    = (z == 0) ? query : (z == 1) ? key_ : value;
    const float* bias = (z == 0) ? bq : (z == 1) ? bk : bv;
    const u16* Wth = Wth_all + (size_t)z * 262144;
    const u16* Wtl = Wtl_all + (size_t)z * 262144;
    u16* Oh = (z == 0) ? qh : (z == 1) ? kh : vb;
    u16* Ol = (z == 0) ? ql : kl;   // unused for z==2

    const int tid = threadIdx.x;
    const int wave = tid >> 6, lane = tid & 63;
    const int quad = lane >> 4, l15 = lane & 15;
    const int row0 = blockIdx.x << 6, col0 = blockIdx.y << 6;
    const int rr = tid >> 2, cc = (tid & 3) << 4;

    const size_t ga = (size_t)(row0 + rr) * HID + cc;
    const size_t gw = (size_t)(col0 + rr) * HID + cc;

    f32x4 acc[4] = {{0.f,0.f,0.f,0.f},{0.f,0.f,0.f,0.f},{0.f,0.f,0.f,0.f},{0.f,0.f,0.f,0.f}};

    for (int k0 = 0; k0 < HID; k0 += 64) {
        float4 af[4];
        #pragma unroll
        for (int e = 0; e < 4; ++e)
            af[e] = *(const float4*)&A[ga + k0 + (e << 2)];
        const short8 wh0 = *(const short8*)&Wth[gw + k0];
        const short8 wh1 = *(const short8*)&Wth[gw + k0 + 8];
        const short8 wl0 = *(const short8*)&Wtl[gw + k0];
        const short8 wl1 = *(const short8*)&Wtl[gw + k0 + 8];
        __syncthreads();
        u16 hA[16], lA[16];
        #pragma unroll
        for (int e = 0; e < 16; ++e) {
            float xv = ((const float*)af)[e];
            u16 hi = f2bf(xv);
            hA[e] = hi;
            lA[e] = f2bf(xv - bf2f(hi));
        }
        *(short8*)&Sa_h[rr * 72 + cc]     = *(short8*)&hA[0];
        *(short8*)&Sa_h[rr * 72 + cc + 8] = *(short8*)&hA[8];
        *(short8*)&Sa_l[rr * 72 + cc]     = *(short8*)&lA[0];
        *(short8*)&Sa_l[rr * 72 + cc + 8] = *(short8*)&lA[8];
        *(short8*)&Sw_h[rr * 72 + cc]     = wh0;
        *(short8*)&Sw_h[rr * 72 + cc + 8] = wh1;
        *(short8*)&Sw_l[rr * 72 + cc]     = wl0;
        *(short8*)&Sw_l[rr * 72 + cc + 8] = wl1;
        __syncthreads();
        #pragma unroll
        for (int s = 0; s < 2; ++s) {
            const int ao = ((wave << 4) + l15) * 72 + (s << 5) + (quad << 3);
            const short8 fa_h = *(const short8*)&Sa_h[ao];
            const short8 fa_l = *(const short8*)&Sa_l[ao];
            #pragma unroll
            for (int nt = 0; nt < 4; ++nt) {
                const int bo = ((nt << 4) + l15) * 72 + (s << 5) + (quad << 3);
                const short8 fb_h = *(const short8*)&Sw_h[bo];
                const short8 fb_l = *(const short8*)&Sw_l[bo];
                acc[nt] = __builtin_amdgcn_mfma_f32_16x16x32_bf16(fa_h, fb_h, acc[nt], 0, 0, 0);
                acc[nt] = __builtin_amdgcn_mfma_f32_16x16x32_bf16(fa_l, fb_h, acc[nt], 0, 0, 0);
                acc[nt] = __builtin_amdgcn_mfma_f32_16x16x32_bf16(fa_h, fb_l, acc[nt], 0, 0, 0);
            }
        }
    }
    #pragma unroll
    for (int nt = 0; nt < 4; ++nt) {
        const int col = col0 + (nt << 4) + l15;
        const float bvv = bias[col];
        #pragma unroll
        for (int r = 0; r < 4; ++r) {
            const size_t row = (size_t)(row0 + (wave << 4) + (quad << 2) + r);
            const float v = acc[nt][r] + bvv;
            if (z == 0) {
                const float sv = v * LG8;
                const u16 hi = f2bf(sv);
                Oh[row * HID + col] = hi;
                Ol[row * HID + col] = f2bf(sv - bf2f(hi));
            } else if (z == 1) {
                const u16 hi = f2bf(v);
                Oh[row * HID + col] = hi;
                Ol[row * HID + col] = f2bf(v - bf2f(hi));
            } else {
                Oh[row * HID + col] = f2bf(v);
            }
        }
    }
}

// ---------------- output projection: fp32 A (x_ws), fp32 out ----------------
__global__ __launch_bounds__(256) void gemm_out_kernel(
    const float* __restrict__ A,
    const u16* __restrict__ Wth, const u16* __restrict__ Wtl,
    const float* __restrict__ bias, float* __restrict__ C)
{
    __shared__ __align__(16) u16 Sa_h[64 * 72];
    __shared__ __align__(16) u16 Sa_l[64 * 72];
    __shared__ __align__(16) u16 Sw_h[64 * 72];
    __shared__ __align__(16) u16 Sw_l[64 * 72];
    const int tid = threadIdx.x;
    const int wave = tid >> 6, lane = tid & 63;
    const int quad = lane >> 4, l15 = lane & 15;
    const int row0 = blockIdx.x << 6, col0 = blockIdx.y << 6;
    const int rr = tid >> 2, cc = (tid & 3) << 4;

    const size_t ga = (size_t)(row0 + rr) * HID + cc;
    const size_t gw = (size_t)(col0 + rr) * HID + cc;

    f32x4 acc[4] = {{0.f,0.f,0.f,0.f},{0.f,0.f,0.f,0.f},{0.f,0.f,0.f,0.f},{0.f,0.f,0.f,0.f}};

    for (int k0 = 0; k0 < HID; k0 += 64) {
        float4 af[4];
        #pragma unroll
        for (int e = 0; e < 4; ++e)
            af[e] = *(const float4*)&A[ga + k0 + (e << 2)];
        const short8 wh0 = *(const short8*)&Wth[gw + k0];
        const short8 wh1 = *(const short8*)&Wth[gw + k0 + 8];
        const short8 wl0 = *(const short8*)&Wtl[gw + k0];
        const short8 wl1 = *(const short8*)&Wtl[gw + k0 + 8];
        __syncthreads();
        u16 hA[16], lA[16];
        #pragma unroll
        for (int e = 0; e < 16; ++e) {
            float xv = ((const float*)af)[e];
            u16 hi = f2bf(xv);
            hA[e] = hi;
            lA[e] = f2bf(xv - bf2f(hi));
        }
        *(short8*)&Sa_h[rr * 72 + cc]     = *(short8*)&hA[0];
        *(short8*)&Sa_h[rr * 72 + cc + 8] = *(short8*)&hA[8];
        *(short8*)&Sa_l[rr * 72 + cc]     = *(short8*)&lA[0];
        *(short8*)&Sa_l[rr * 72 + cc + 8] = *(short8*)&lA[8];
        *(short8*)&Sw_h[rr * 72 + cc]     = wh0;
        *(short8*)&Sw_h[rr * 72 + cc + 8] = wh1;
        *(short8*)&Sw_l[rr * 72 + cc]     = wl0;
        *(short8*)&Sw_l[rr * 72 + cc + 8] = wl1;
        __syncthreads();
        #pragma unroll
        for (int s = 0; s < 2; ++s) {
            const int ao = ((wave << 4) + l15) * 72 + (s << 5) + (quad << 3);
            const short8 fa_h = *(const short8*)&Sa_h[ao];
            const short8 fa_l = *(const short8*)&Sa_l[ao];
            #pragma unroll
            for (int nt = 0; nt < 4; ++nt) {
                const int bo = ((nt << 4) + l15) * 72 + (s << 5) + (quad << 3);
                const short8 fb_h = *(const short8*)&Sw_h[bo];
                const short8 fb_l = *(const short8*)&Sw_l[bo];
                acc[nt] = __builtin_amdgcn_mfma_f32_16x16x32_bf16(fa_h, fb_h, acc[nt], 0, 0, 0);
                acc[nt] = __builtin_amdgcn_mfma_f32_16x16x32_bf16(fa_l, fb_h, acc[nt], 0, 0, 0);
                acc[nt] = __builtin_amdgcn_mfma_f32_16x16x32_bf16(fa_h, fb_l, acc[nt], 0, 0, 0);
            }
        }
    }
    #pragma unroll
    for (int nt = 0; nt < 4; ++nt) {
        const int col = col0 + (nt << 4) + l15;
        const float bvv = bias[col];
        #pragma unroll
        for (int r = 0; r < 4; ++r) {
            const size_t row = (size_t)(row0 + (wave << 4) + (quad << 2) + r);
            C[row * HID + col] = acc[nt][r] + bvv;
        }
    }
}

// ---------------- rel dots from bf16 hi/lo (q prescaled by LG8) ----------------
__global__ __launch_bounds__(256) void rel_dots_kernel(
    const u16* __restrict__ qh, const u16* __restrict__ ql,
    const u16* __restrict__ kh, const u16* __restrict__ kl,
    const float* __restrict__ rel_table, float* __restrict__ dqk)
{
    const int w = blockIdx.x * 4 + (threadIdx.x >> 6);
    const int lane = threadIdx.x & 63;
    const int h = w % NHEAD;
    const int is = w / NHEAD;            // b*SEQ + i
    const int b = is / SEQ;
    const int i = is % SEQ;
    const size_t base = (size_t)is * HID + h * 64 + lane;
    const float qs = bf2f(qh[base]) + bf2f(ql[base]);   // = q * LG8
    const float kv = bf2f(kh[base]) + bf2f(kl[base]);   // = k
    const float s = qs + LG8 * kv;
    float p0 = s * rel_table[lane];
    float p1 = s * rel_table[64 + lane];
    float p2 = s * rel_table[128 + lane];
    #pragma unroll
    for (int off = 32; off; off >>= 1) {
        p0 += __shfl_xor(p0, off);
        p1 += __shfl_xor(p1, off);
        p2 += __shfl_xor(p2, off);
    }
    if (lane == 0) {
        size_t o = (((size_t)b * NHEAD + h) * SEQ + i) << 2;
        dqk[o + 0] = p0; dqk[o + 1] = p1; dqk[o + 2] = p2;
    }
}

// ---------------- pass 1: per-row denominator (no logits write) ----------------
__global__ __launch_bounds__(256) void attn_stats_kernel(
    const u16* __restrict__ qh, const u16* __restrict__ ql,
    const u16* __restrict__ kh, const u16* __restrict__ kl,
    const float* __restrict__ dqk, const u8* __restrict__ pm,
    float* __restrict__ invl)
{
    __shared__ __align__(16) u16 Kh[64 * 72];
    __shared__ __align__(16) u16 Kl[64 * 72];
    __shared__ __align__(16) u8  PM[64 * 64];
    __shared__ float Ds[64][4];
    const int tid = threadIdx.x;
    const int wave = tid >> 6, lane = tid & 63;
    const int quad = lane >> 4, l15 = lane & 15;
    const int b = blockIdx.z, h = blockIdx.y, i0 = blockIdx.x << 6;
    const size_t bh = (size_t)(b * NHEAD + h);

    {
        const int i = tid >> 2, r = tid & 3;
        Ds[i][r] = (r == 3) ? MASKV : dqk[((bh * SEQ + i0 + i) << 2) + r];
    }
    const int irow = (wave << 4) + l15;
    const size_t qbase = ((size_t)(b * SEQ + i0 + irow)) * HID + h * 64 + (quad << 3);
    const short8 aqh0 = *(const short8*)&qh[qbase];
    const short8 aqh1 = *(const short8*)&qh[qbase + 32];
    const short8 aql0 = *(const short8*)&ql[qbase];
    const short8 aql1 = *(const short8*)&ql[qbase + 32];

    float srow[4] = {0.f, 0.f, 0.f, 0.f};

    for (int jt = 0; jt < SEQ / 64; ++jt) {
        const int j0 = jt << 6;
        __syncthreads();
        {
            const int rr = tid >> 3, cc = (tid & 7) << 3;
            const size_t g = ((size_t)(b * SEQ + j0 + rr)) * HID + h * 64 + cc;
            *(short8*)&Kh[rr * 72 + cc] = *(const short8*)&kh[g];
            *(short8*)&Kl[rr * 72 + cc] = *(const short8*)&kl[g];
            const size_t g2 = g + (size_t)32 * HID;
            *(short8*)&Kh[(rr + 32) * 72 + cc] = *(const short8*)&kh[g2];
            *(short8*)&Kl[(rr + 32) * 72 + cc] = *(const short8*)&kl[g2];
        }
        {
            const int r = tid >> 2, c = (tid & 3) << 4;
            *(uint4*)&PM[r * 64 + c] =
                *(const uint4*)&pm[((size_t)b * SEQ + i0 + r) * SEQ + j0 + c];
        }
        __syncthreads();

        #pragma unroll
        for (int sub = 0; sub < 4; ++sub) {
            const int n = (sub << 4) + l15;
            const short8 bh0 = *(const short8*)&Kh[n * 72 + (quad << 3)];
            const short8 bh1 = *(const short8*)&Kh[n * 72 + 32 + (quad << 3)];
            const short8 bl0 = *(const short8*)&Kl[n * 72 + (quad << 3)];
            const short8 bl1 = *(const short8*)&Kl[n * 72 + 32 + (quad << 3)];
            f32x4 acc = {0.f, 0.f, 0.f, 0.f};
            acc = __builtin_amdgcn_mfma_f32_16x16x32_bf16(aqh0, bh0, acc, 0, 0, 0);
            acc = __builtin_amdgcn_mfma_f32_16x16x32_bf16(aqh1, bh1, acc, 0, 0, 0);
            acc = __builtin_amdgcn_mfma_f32_16x16x32_bf16(aql0, bh0, acc, 0, 0, 0);
            acc = __builtin_amdgcn_mfma_f32_16x16x32_bf16(aql1, bh1, acc, 0, 0, 0);
            acc = __builtin_amdgcn_mfma_f32_16x16x32_bf16(aqh0, bl0, acc, 0, 0, 0);
            acc = __builtin_amdgcn_mfma_f32_16x16x32_bf16(aqh1, bl1, acc, 0, 0, 0);
            #pragma unroll
            for (int r = 0; r < 4; ++r) {
                const int il = (wave << 4) + (quad << 2) + r;
                const u8 p = PM[il * 64 + (sub << 4) + l15];
                srow[r] += exp2f(acc[r] + Ds[il][p]);
            }
        }
    }
    #pragma unroll
    for (int r = 0; r < 4; ++r) {
        float s = srow[r];
        s += __shfl_xor(s, 1); s += __shfl_xor(s, 2);
        s += __shfl_xor(s, 4); s += __shfl_xor(s, 8);
        if (l15 == 0)
            invl[bh * SEQ + i0 + (wave << 4) + (quad << 2) + r] = 1.0f / s;
    }
}

// ---------------- pass 2: recompute logits, write attn once, fused PV ----------------
__global__ __launch_bounds__(256) void attn_fused_kernel(
    const u16* __restrict__ qh, const u16* __restrict__ ql,
    const u16* __restrict__ kh, const u16* __restrict__ kl,
    const u16* __restrict__ vb, const float* __restrict__ dqk,
    const u8* __restrict__ pm, const float* __restrict__ invl,
    float* __restrict__ attn, float* __restrict__ x)
{
    __shared__ __align__(16) u16 Kh[64 * 72];
    __shared__ __align__(16) u16 Kl[64 * 72];
    __shared__ __align__(16) u16 VtT[64 * 72];
    __shared__ __align__(16) u16 Pst[4][16 * 72];
    __shared__ __align__(16) u8  PM[64 * 64];
    __shared__ float Ds[64][4];
    const int tid = threadIdx.x;
    const int wave = tid >> 6, lane = tid & 63;
    const int quad = lane >> 4, l15 = lane & 15;
    const int b = blockIdx.z, h = blockIdx.y, i0 = blockIdx.x << 6;
    const size_t bh = (size_t)(b * NHEAD + h);

    {
        const int i = tid >> 2, r = tid & 3;
        Ds[i][r] = (r == 3) ? MASKV : dqk[((bh * SEQ + i0 + i) << 2) + r];
    }
    float inv_r[4];
    #pragma unroll
    for (int r = 0; r < 4; ++r)
        inv_r[r] = invl[bh * SEQ + i0 + (wave << 4) + (quad << 2) + r];

    const int irow = (wave << 4) + l15;
    const size_t qbase = ((size_t)(b * SEQ + i0 + irow)) * HID + h * 64 + (quad << 3);
    const short8 aqh0 = *(const short8*)&qh[qbase];
    const short8 aqh1 = *(const short8*)&qh[qbase + 32];
    const short8 aql0 = *(const short8*)&ql[qbase];
    const short8 aql1 = *(const short8*)&ql[qbase + 32];

    f32x4 accX[4] = {{0.f,0.f,0.f,0.f},{0.f,0.f,0.f,0.f},{0.f,0.f,0.f,0.f},{0.f,0.f,0.f,0.f}};

    for (int jt = 0; jt < SEQ / 64; ++jt) {
        const int j0 = jt << 6;
        __syncthreads();
        {
            const int rr = tid >> 3, cc = (tid & 7) << 3;
            const size_t g = ((size_t)(b * SEQ + j0 + rr)) * HID + h * 64 + cc;
            *(short8*)&Kh[rr * 72 + cc] = *(const short8*)&kh[g];
            *(short8*)&Kl[rr * 72 + cc] = *(const short8*)&kl[g];
            const size_t g2 = g + (size_t)32 * HID;
            *(short8*)&Kh[(rr + 32) * 72 + cc] = *(const short8*)&kh[g2];
            *(short8*)&Kl[(rr + 32) * 72 + cc] = *(const short8*)&kl[g2];
        }
        {
            const int r = tid >> 2, c = (tid & 3) << 4;
            *(uint4*)&PM[r * 64 + c] =
                *(const uint4*)&pm[((size_t)b * SEQ + i0 + r) * SEQ + j0 + c];
        }
        {   // stage V^T tile (d-major) for PV A-operand
            const int jr = tid & 63, d0 = (tid >> 6) << 4;
            const size_t g = ((size_t)(b * SEQ + j0 + jr)) * HID + h * 64 + d0;
            const short8 v0 = *(const short8*)&vb[g];
            const short8 v1 = *(const short8*)&vb[g + 8];
            #pragma unroll
            for (int e = 0; e < 8; ++e) {
                VtT[(d0 + e) * 72 + jr]     = (u16)v0[e];
                VtT[(d0 + 8 + e) * 72 + jr] = (u16)v1[e];
            }
        }
        __syncthreads();

        #pragma unroll
        for (int sub = 0; sub < 4; ++sub) {
            const int n = (sub << 4) + l15;
            const short8 bh0 = *(const short8*)&Kh[n * 72 + (quad << 3)];
            const short8 bh1 = *(const short8*)&Kh[n * 72 + 32 + (quad << 3)];
            const short8 bl0 = *(const short8*)&Kl[n * 72 + (quad << 3)];
            const short8 bl1 = *(const short8*)&Kl[n * 72 + 32 + (quad << 3)];
            f32x4 acc = {0.f, 0.f, 0.f, 0.f};
            acc = __builtin_amdgcn_mfma_f32_16x16x32_bf16(aqh0, bh0, acc, 0, 0, 0);
            acc = __builtin_amdgcn_mfma_f32_16x16x32_bf16(aqh1, bh1, acc, 0, 0, 0);
            acc = __builtin_amdgcn_mfma_f32_16x16x32_bf16(aql0, bh0, acc, 0, 0, 0);
            acc = __builtin_amdgcn_mfma_f32_16x16x32_bf16(aql1, bh1, acc, 0, 0, 0);
            acc = __builtin_amdgcn_mfma_f32_16x16x32_bf16(aqh0, bl0, acc, 0, 0, 0);
            acc = __builtin_amdgcn_mfma_f32_16x16x32_bf16(aqh1, bl1, acc, 0, 0, 0);
            #pragma unroll
            for (int r = 0; r < 4; ++r) {
                const int il = (wave << 4) + (quad << 2) + r;
                const u8 p = PM[il * 64 + (sub << 4) + l15];
                const float pr = exp2f(acc[r] + Ds[il][p]) * inv_r[r];
                attn[(bh * SEQ + i0 + il) * SEQ + j0 + (sub << 4) + l15] = pr;
                Pst[wave][((quad << 2) + r) * 72 + (sub << 4) + l15] = f2bf(pr);
            }
        }
        // PV: X^T = V^T @ P^T  (wave-private P strip; same-wave LDS ordering)
        const short8 bp0 = *(const short8*)&Pst[wave][l15 * 72 + (quad << 3)];
        const short8 bp1 = *(const short8*)&Pst[wave][l15 * 72 + 32 + (quad << 3)];
        #pragma unroll
        for (int m = 0; m < 4; ++m) {
            const short8 av0 = *(const short8*)&VtT[((m << 4) + l15) * 72 + (quad << 3)];
            const short8 av1 = *(const short8*)&VtT[((m << 4) + l15) * 72 + 32 + (quad << 3)];
            accX[m] = __builtin_amdgcn_mfma_f32_16x16x32_bf16(av0, bp0, accX[m], 0, 0, 0);
            accX[m] = __builtin_amdgcn_mfma_f32_16x16x32_bf16(av1, bp1, accX[m], 0, 0, 0);
        }
    }
    const size_t xrow = ((size_t)(b * SEQ + i0 + (wave << 4) + l15)) * HID + h * 64;
    #pragma unroll
    for (int m = 0; m < 4; ++m) {
        *(f32x4*)&x[xrow + (m << 4) + (quad << 2)] = accX[m];
    }
}

extern "C" void kernel_launch(void* const* d_in, const int* in_sizes, int n_in,
                              void* d_out, int out_size, void* d_ws, size_t ws_size,
                              hipStream_t stream) {
    (void)in_sizes; (void)n_in; (void)out_size; (void)ws_size;
    const float* query = (const float*)d_in[0];
    const float* key_  = (const float*)d_in[1];
    const float* value = (const float*)d_in[2];
    const u8*    mask  = (const u8*)d_in[3];
    const int*   pos   = (const int*)d_in[4];
    const float* Wq = (const float*)d_in[5];
    const float* bq = (const float*)d_in[6];
    const float* Wk = (const float*)d_in[7];
    const float* bk = (const float*)d_in[8];
    const float* Wv = (const float*)d_in[9];
    const float* bv = (const float*)d_in[10];
    const float* Wo = (const float*)d_in[11];
    const float* bo = (const float*)d_in[12];
    const float* rel_table = (const float*)d_in[13];

    float* out  = (float*)d_out;
    float* attn = out + (size_t)BATCH * SEQ * HID;

    // ws layout: qh|ql|kh|kl|vb bf16 (4MB ea) | dqk 512KB | invl 128KB | pm 8MB |
    //            x_ws 8MB | Wth 2MB | Wtl 2MB   ~40.6MB
    u16* qh = (u16*)d_ws;
    u16* ql = qh + (size_t)2097152;
    u16* kh = ql + (size_t)2097152;
    u16* kl = kh + (size_t)2097152;
    u16* vb = kl + (size_t)2097152;
    float* dqk  = (float*)(vb + (size_t)2097152);
    float* invl = dqk + (size_t)131072;
    u8*  pm  = (u8*)(invl + (size_t)32768);
    float* x_ws = (float*)(pm + (size_t)8388608);
    u16* Wth = (u16*)(x_ws + (size_t)2097152);
    u16* Wtl = Wth + (size_t)1048576;

    const dim3 blk(256);

    misc_prep_kernel<<<dim3(256 + 8192), blk, 0, stream>>>(
        Wq, Wk, Wv, Wo, Wth, Wtl, pos, mask, pm);
    gemm_qkv_kernel<<<dim3(64, 8, 3), blk, 0, stream>>>(
        query, key_, value, Wth, Wtl, bq, bk, bv, qh, ql, kh, kl, vb);
    rel_dots_kernel<<<dim3(BATCH * SEQ * NHEAD / 4), blk, 0, stream>>>(
        qh, ql, kh, kl, rel_table, dqk);
    attn_stats_kernel<<<dim3(SEQ / 64, NHEAD, BATCH), blk, 0, stream>>>(
        qh, ql, kh, kl, dqk, pm, invl);
    attn_fused_kernel<<<dim3(SEQ / 64, NHEAD, BATCH), blk, 0, stream>>>(
        qh, ql, kh, kl, vb, dqk, pm, invl, attn, x_ws);
    gemm_out_kernel<<<dim3(64, 8), blk, 0, stream>>>(
        x_ws, Wth + (size_t)3 * 262144, Wtl + (size_t)3 * 262144, bo, out);
}